// Round 1
// baseline (725.269 us; speedup 1.0000x reference)
//
#include <hip/hip_runtime.h>

// Shapes: B=4, W=64, H=64, C=256, M=32, D=32. TEMPERATURE = 8.0.
// q: [B,W,H,M,D] f32; v: [B,W,H,C,M] f32; k: [B,W,H,D,1] f32
// out: [B,C,W,H] f32
// Per pixel p = b*4096 + wh:
//   logit[m] = sum_d q[p,m,d] * k[p,d] / 8
//   attn = softmax_m(logit)
//   out[b,c,wh] = sum_m v[p,c,m] * attn[m]

#define TEMP_INV 0.125f

__global__ __launch_bounds__(256) void sdpa_kernel(
    const float* __restrict__ q,
    const float* __restrict__ v,
    const float* __restrict__ k,
    float* __restrict__ out)
{
    const int p = blockIdx.x;           // pixel: b*4096 + wh
    const int t = threadIdx.x;
    const int b  = p >> 12;             // p / (64*64)
    const int wh = p & 4095;

    __shared__ float s_k[32];
    __shared__ float s_logit[32];
    __shared__ float s_attn[32];

    if (t < 32) s_k[t] = k[p * 32 + t] * TEMP_INV;
    __syncthreads();

    // ---- logits: thread t handles m = t>>3, d-chunk j = t&7 (4 d's) ----
    const int j = t & 7;
    {
        // q float4 flat index: (p*1024 + m*32 + j*4)/4 = p*256 + t  (coalesced)
        const float4 q4 = ((const float4*)q)[p * 256 + t];
        float partial = q4.x * s_k[j * 4 + 0] + q4.y * s_k[j * 4 + 1]
                      + q4.z * s_k[j * 4 + 2] + q4.w * s_k[j * 4 + 3];
        partial += __shfl_down(partial, 4, 8);
        partial += __shfl_down(partial, 2, 8);
        partial += __shfl_down(partial, 1, 8);
        if (j == 0) s_logit[t >> 3] = partial;
    }
    __syncthreads();

    // ---- softmax over the 32 slots (axis M), first 32 lanes ----
    if (t < 32) {
        float l = s_logit[t];
        float mx = l;
        #pragma unroll
        for (int off = 16; off; off >>= 1)
            mx = fmaxf(mx, __shfl_xor(mx, off, 32));
        float e = __expf(l - mx);
        float sum = e;
        #pragma unroll
        for (int off = 16; off; off >>= 1)
            sum += __shfl_xor(sum, off, 32);
        s_attn[t] = e / sum;
    }
    __syncthreads();

    // ---- out[c] = sum_m v[c,m] * attn[m] ----
    // float4 flat index f4 = t + 256*i: m-chunk = (t&7)*4 fixed per thread,
    // c = (t>>3) + 32*i. Every global load is a coalesced 1 KiB transaction.
    const float a0 = s_attn[j * 4 + 0];
    const float a1 = s_attn[j * 4 + 1];
    const float a2 = s_attn[j * 4 + 2];
    const float a3 = s_attn[j * 4 + 3];

    const float4* v4p = (const float4*)v + (size_t)p * 2048;
    float acc[8];
    #pragma unroll
    for (int i = 0; i < 8; ++i) {
        const float4 v4 = v4p[t + 256 * i];
        acc[i] = v4.x * a0 + v4.y * a1 + v4.z * a2 + v4.w * a3;
    }
    #pragma unroll
    for (int i = 0; i < 8; ++i) {
        acc[i] += __shfl_down(acc[i], 4, 8);
        acc[i] += __shfl_down(acc[i], 2, 8);
        acc[i] += __shfl_down(acc[i], 1, 8);
    }
    if (j == 0) {
        const int c0 = t >> 3;
        #pragma unroll
        for (int i = 0; i < 8; ++i) {
            // out[b, c0+32i, wh]  (scattered 4B writes; see round-2 note)
            out[(b * 256 + (c0 + 32 * i)) * 4096 + wh] = acc[i];
        }
    }
}

extern "C" void kernel_launch(void* const* d_in, const int* in_sizes, int n_in,
                              void* d_out, int out_size, void* d_ws, size_t ws_size,
                              hipStream_t stream) {
    const float* q = (const float*)d_in[0];
    const float* v = (const float*)d_in[1];
    const float* k = (const float*)d_in[2];
    float* out = (float*)d_out;
    sdpa_kernel<<<16384, 256, 0, stream>>>(q, v, k, out);
}

// Round 2
// 717.594 us; speedup vs baseline: 1.0107x; 1.0107x over previous
//
#include <hip/hip_runtime.h>

// Shapes: B=4, W=64, H=64, C=256, M=32, D=32. TEMPERATURE = 8.0.
// q: [B,W,H,M,D] f32; v: [B,W,H,C,M] f32; k: [B,W,H,D,1] f32
// out: [B,C,W,H] f32
// Per pixel p = b*4096 + wh:
//   logit[m] = sum_d q[p,m,d] * k[p,d] / 8
//   attn = softmax_m(logit)
//   out[b,c,wh] = sum_m v[p,c,m] * attn[m]
//
// v2: 16 pixels per block -> coalesced full-line output writes via LDS tile,
// batched k loads, more loads in flight per thread.

#define TEMP_INV 0.125f
#define G 16  // consecutive wh pixels per block (4096 % 16 == 0, same b)

__global__ __launch_bounds__(256) void sdpa_kernel(
    const float* __restrict__ q,
    const float* __restrict__ v,
    const float* __restrict__ k,
    float* __restrict__ out)
{
    const int t   = threadIdx.x;
    const int p0  = blockIdx.x * G;     // first pixel of this block
    const int b   = p0 >> 12;
    const int wh0 = p0 & 4095;          // multiple of 16

    __shared__ float s_k[G * 32];       // pre-scaled by 1/T
    __shared__ float s_logit[G * 32];
    __shared__ float s_attn[G * 32];
    __shared__ float s_out[256 * 17];   // [c][g], +1 float4-ish pad (17) kills bank conflicts

    // ---- Phase A: k for all 16 pixels (512 floats = 128 float4, coalesced) ----
    if (t < 128) {
        float4 k4 = ((const float4*)k)[p0 * 8 + t];
        k4.x *= TEMP_INV; k4.y *= TEMP_INV; k4.z *= TEMP_INV; k4.w *= TEMP_INV;
        ((float4*)s_k)[t] = k4;
    }
    __syncthreads();

    // ---- Phase B: logits. thread t = (m = t>>3, d-chunk j = t&7) per pixel ----
    const int j = t & 7;
    const int m = t >> 3;
    #pragma unroll 2
    for (int g = 0; g < G; ++g) {
        const float4 q4 = ((const float4*)q)[(p0 + g) * 256 + t];  // coalesced
        const float* kg = &s_k[g * 32 + j * 4];
        float partial = q4.x * kg[0] + q4.y * kg[1] + q4.z * kg[2] + q4.w * kg[3];
        partial += __shfl_down(partial, 4, 8);
        partial += __shfl_down(partial, 2, 8);
        partial += __shfl_down(partial, 1, 8);
        if (j == 0) s_logit[g * 32 + m] = partial;
    }
    __syncthreads();

    // ---- Phase C: softmax over m (32 slots) per pixel; 8 pixels/pass x2 ----
    {
        const int mm = t & 31;
        #pragma unroll
        for (int r = 0; r < 2; ++r) {
            const int g = (t >> 5) + r * 8;
            float l = s_logit[g * 32 + mm];
            float mx = l;
            #pragma unroll
            for (int off = 16; off; off >>= 1)
                mx = fmaxf(mx, __shfl_xor(mx, off, 32));
            float e = __expf(l - mx);
            float s = e;
            #pragma unroll
            for (int off = 16; off; off >>= 1)
                s += __shfl_xor(s, off, 32);
            s_attn[g * 32 + mm] = e / s;
        }
    }
    __syncthreads();

    // ---- Phase D: out[c,g] = sum_m v[p,c,m]*attn[g,m], accumulate in LDS ----
    // thread t = (c0 = t>>3, m-chunk j = t&7); v float4 idx t+256*i is a
    // contiguous 1 KiB wave transaction.
    const int c0 = t >> 3;
    #pragma unroll 2
    for (int g = 0; g < G; ++g) {
        const float* ag = &s_attn[g * 32 + j * 4];
        const float a0 = ag[0], a1 = ag[1], a2 = ag[2], a3 = ag[3];
        const float4* v4p = (const float4*)v + (size_t)(p0 + g) * 2048;
        float acc[8];
        #pragma unroll
        for (int i = 0; i < 8; ++i) {
            const float4 v4 = v4p[t + 256 * i];
            acc[i] = v4.x * a0 + v4.y * a1 + v4.z * a2 + v4.w * a3;
        }
        #pragma unroll
        for (int i = 0; i < 8; ++i) {
            acc[i] += __shfl_down(acc[i], 4, 8);
            acc[i] += __shfl_down(acc[i], 2, 8);
            acc[i] += __shfl_down(acc[i], 1, 8);
        }
        if (j == 0) {
            #pragma unroll
            for (int i = 0; i < 8; ++i)
                s_out[(c0 + 32 * i) * 17 + g] = acc[i];  // banks 17*c%32: conflict-free
        }
    }
    __syncthreads();

    // ---- Phase E: write out[b, c, wh0..wh0+15] — full 64B lines per c ----
    // lane group of 4 covers one 64 B row; each line written entirely by this block.
    {
        const int c  = t >> 2;   // 0..63 (+64*i)
        const int gc = t & 3;    // float4 within the 16-pixel row
        #pragma unroll
        for (int i = 0; i < 4; ++i) {
            const int cc = c + 64 * i;
            const float* so = &s_out[cc * 17 + gc * 4];
            const float4 o4 = make_float4(so[0], so[1], so[2], so[3]);
            ((float4*)out)[(size_t)(b * 256 + cc) * 1024 + (wh0 >> 2) + gc] = o4;
        }
    }
}

extern "C" void kernel_launch(void* const* d_in, const int* in_sizes, int n_in,
                              void* d_out, int out_size, void* d_ws, size_t ws_size,
                              hipStream_t stream) {
    const float* q = (const float*)d_in[0];
    const float* v = (const float*)d_in[1];
    const float* k = (const float*)d_in[2];
    float* out = (float*)d_out;
    sdpa_kernel<<<16384 / G, 256, 0, stream>>>(q, v, k, out);
}

// Round 3
// 682.903 us; speedup vs baseline: 1.0620x; 1.0508x over previous
//
#include <hip/hip_runtime.h>

// Shapes: B=4, W=64, H=64, C=256, M=32, D=32. TEMPERATURE = 8.0.
// q: [B,W,H,M,D] f32; v: [B,W,H,C,M] f32; k: [B,W,H,D,1] f32
// out: [B,C,W,H] f32
// Per pixel p = b*4096 + wh:
//   logit[m] = sum_d q[p,m,d] * k[p,d] / 8
//   attn = softmax_m(logit)
//   out[b,c,wh] = sum_m v[p,c,m] * attn[m]
//
// v3: v2 (16 px/block, coalesced full-line writes) + non-temporal loads for
// the zero-reuse q/v streams and non-temporal out stores (no L2 pollution,
// no partial-line RMW), deeper q-phase unroll.

#define TEMP_INV 0.125f
#define G 16  // consecutive wh pixels per block (same b; 64B out line == 16 px)

typedef float f4 __attribute__((ext_vector_type(4)));

__global__ __launch_bounds__(256) void sdpa_kernel(
    const float* __restrict__ q,
    const float* __restrict__ v,
    const float* __restrict__ k,
    float* __restrict__ out)
{
    const int t   = threadIdx.x;
    const int p0  = blockIdx.x * G;
    const int b   = p0 >> 12;
    const int wh0 = p0 & 4095;

    __shared__ float s_k[G * 32];
    __shared__ float s_logit[G * 32];
    __shared__ float s_attn[G * 32];
    __shared__ float s_out[256 * 17];   // [c][g], pad 17 -> conflict-free

    // ---- Phase A: k for all 16 pixels (128 float4, coalesced; reused -> normal load)
    if (t < 128) {
        f4 k4 = ((const f4*)k)[p0 * 8 + t];
        k4 *= TEMP_INV;
        ((f4*)s_k)[t] = k4;
    }
    __syncthreads();

    // ---- Phase B: logits. thread t = (m = t>>3, d-chunk j = t&7) per pixel
    const int j = t & 7;
    const int m = t >> 3;
    #pragma unroll 4
    for (int g = 0; g < G; ++g) {
        const f4 q4 = __builtin_nontemporal_load((const f4*)q + (p0 + g) * 256 + t);
        const float* kg = &s_k[g * 32 + j * 4];
        float partial = q4.x * kg[0] + q4.y * kg[1] + q4.z * kg[2] + q4.w * kg[3];
        partial += __shfl_down(partial, 4, 8);
        partial += __shfl_down(partial, 2, 8);
        partial += __shfl_down(partial, 1, 8);
        if (j == 0) s_logit[g * 32 + m] = partial;
    }
    __syncthreads();

    // ---- Phase C: softmax over the 32 slots per pixel; 8 pixels/pass x2
    {
        const int mm = t & 31;
        #pragma unroll
        for (int r = 0; r < 2; ++r) {
            const int g = (t >> 5) + r * 8;
            float l = s_logit[g * 32 + mm];
            float mx = l;
            #pragma unroll
            for (int off = 16; off; off >>= 1)
                mx = fmaxf(mx, __shfl_xor(mx, off, 32));
            float e = __expf(l - mx);
            float s = e;
            #pragma unroll
            for (int off = 16; off; off >>= 1)
                s += __shfl_xor(s, off, 32);
            s_attn[g * 32 + mm] = e / s;
        }
    }
    __syncthreads();

    // ---- Phase D: out[c,g] = sum_m v[p,c,m]*attn[g,m]; v loads coalesced 1 KiB/wave
    const int c0 = t >> 3;
    #pragma unroll 2
    for (int g = 0; g < G; ++g) {
        const float* ag = &s_attn[g * 32 + j * 4];
        const float a0 = ag[0], a1 = ag[1], a2 = ag[2], a3 = ag[3];
        const f4* v4p = (const f4*)v + (size_t)(p0 + g) * 2048;
        float acc[8];
        #pragma unroll
        for (int i = 0; i < 8; ++i) {
            const f4 v4 = __builtin_nontemporal_load(v4p + t + 256 * i);
            acc[i] = v4.x * a0 + v4.y * a1 + v4.z * a2 + v4.w * a3;
        }
        #pragma unroll
        for (int i = 0; i < 8; ++i) {
            acc[i] += __shfl_down(acc[i], 4, 8);
            acc[i] += __shfl_down(acc[i], 2, 8);
            acc[i] += __shfl_down(acc[i], 1, 8);
        }
        if (j == 0) {
            #pragma unroll
            for (int i = 0; i < 8; ++i)
                s_out[(c0 + 32 * i) * 17 + g] = acc[i];
        }
    }
    __syncthreads();

    // ---- Phase E: write out[b, c, wh0..wh0+15] — full 64 B lines, non-temporal
    {
        const int c  = t >> 2;   // 0..63 (+64*i)
        const int gc = t & 3;    // float4 within the 16-px row
        #pragma unroll
        for (int i = 0; i < 4; ++i) {
            const int cc = c + 64 * i;
            const float* so = &s_out[cc * 17 + gc * 4];
            f4 o4 = { so[0], so[1], so[2], so[3] };
            __builtin_nontemporal_store(
                o4, (f4*)out + (size_t)(b * 256 + cc) * 1024 + (wh0 >> 2) + gc);
        }
    }
}

extern "C" void kernel_launch(void* const* d_in, const int* in_sizes, int n_in,
                              void* d_out, int out_size, void* d_ws, size_t ws_size,
                              hipStream_t stream) {
    const float* q = (const float*)d_in[0];
    const float* v = (const float*)d_in[1];
    const float* k = (const float*)d_in[2];
    float* out = (float*)d_out;
    sdpa_kernel<<<16384 / G, 256, 0, stream>>>(q, v, k, out);
}